// Round 6
// baseline (186.093 us; speedup 1.0000x reference)
//
#include <hip/hip_runtime.h>
#include <math.h>

namespace {

constexpr int NA = 120;
constexpr int NH = 60;    // angles per half-block
constexpr int LR = 128;
constexpr int LZ = 192;
constexpr int UW = 192;   // padded u-width of the pair buffer
constexpr float CTR = 63.5f; // unpadded-space center: (LP-1)/2 - PAD = 90.5 - 27

typedef float v2f __attribute__((ext_vector_type(2)));

// ============ pair-buffer pre-pass =========================================
// pb[a][u'][z] = (fp8(v[a][u'-32][z]-0.5), fp8(v[a][u'-31][z]-0.5)), 2 B/pair.
// Rows outside [0,128) are the zero-pad region -> stored fp8(0-0.5)=fp8(-0.5),
// so the main kernel needs NO masks: w*(v-0.5) + 0.5*w == w*v for v==0 too.
__global__ __launch_bounds__(256) void cvt_pairs(const float* __restrict__ img,
                                                 unsigned short* __restrict__ pb) {
    const int idx = blockIdx.x * 256 + threadIdx.x; // 120*192*24 = 552960 exact
    const int zc = idx % (LZ / 8);
    const int t  = idx / (LZ / 8);
    const int up = t % UW;
    const int a  = t / UW;
    const int r0 = up - 32;
    const int r1 = up - 31;
    const int z0 = zc * 8;

    float v0[8], v1[8];
    if (r0 >= 0 && r0 < LR) {
        const float4 x = *reinterpret_cast<const float4*>(img + (a * LR + r0) * LZ + z0);
        const float4 y = *reinterpret_cast<const float4*>(img + (a * LR + r0) * LZ + z0 + 4);
        v0[0]=x.x; v0[1]=x.y; v0[2]=x.z; v0[3]=x.w;
        v0[4]=y.x; v0[5]=y.y; v0[6]=y.z; v0[7]=y.w;
    } else {
#pragma unroll
        for (int j = 0; j < 8; ++j) v0[j] = 0.f;
    }
    if (r1 >= 0 && r1 < LR) {
        const float4 x = *reinterpret_cast<const float4*>(img + (a * LR + r1) * LZ + z0);
        const float4 y = *reinterpret_cast<const float4*>(img + (a * LR + r1) * LZ + z0 + 4);
        v1[0]=x.x; v1[1]=x.y; v1[2]=x.z; v1[3]=x.w;
        v1[4]=y.x; v1[5]=y.y; v1[6]=y.z; v1[7]=y.w;
    } else {
#pragma unroll
        for (int j = 0; j < 8; ++j) v1[j] = 0.f;
    }

    uint4 o;
    unsigned int* od = &o.x;
#pragma unroll
    for (int d = 0; d < 4; ++d) {
        // dword d = bytes (t0_z, t1_z, t0_{z+1}, t1_{z+1}) for z = 2d
        int w = __builtin_amdgcn_cvt_pk_fp8_f32(v0[2*d] - 0.5f, v1[2*d] - 0.5f, 0, false);
        w = __builtin_amdgcn_cvt_pk_fp8_f32(v0[2*d+1] - 0.5f, v1[2*d+1] - 0.5f, w, true);
        od[d] = (unsigned int)w;
    }
    *reinterpret_cast<uint4*>(pb + ((size_t)(a * UW + up) * LZ + z0)) = o;
}

// ============ main: half-angle blocks, pair taps, depth-4 ring ==============
struct __align__(16) GeoP {
    float w0, w1;
    int voff; // byte offset of the pair row in pb
    int pad;
};

__global__ __launch_bounds__(192, 8) void bp_v6(const unsigned char* __restrict__ pb,
                                                float* __restrict__ out) {
    __shared__ float2 s_cs[NH];
    __shared__ GeoP s_geo[NH + 4][8]; // +4 zero-weight pad entries (branch-free ring)

    const int tid = threadIdx.x; // 0..191

    // 4096 blocks; XCD-aware chunked swizzle (bijective: 4096 % 8 == 0)
    const int bid = blockIdx.x;
    const int swz = (bid & 7) * 512 + (bid >> 3);
    const int half = swz >> 11;      // 0..1 (angle half)
    const int rem  = swz & 2047;
    const int y  = rem >> 4;         // 0..127
    const int xg = (rem & 15) << 3;  // x base, step 8

    if (tid < NH) {
        const int a = half * NH + tid;
        const float ang = (float)a * (float)(2.0 * M_PI / (double)NA);
        const float phi = (float)(1.5 * M_PI) - ang;
        s_cs[tid] = make_float2(cosf(phi), sinf(phi));
    }
    __syncthreads();

    const float Y = (float)y - CTR;
    for (int e = tid; e < 8 * (NH + 4); e += 192) {
        const int p = e & 7;
        const int t = e >> 3;
        GeoP g;
        if (t < NH) {
            const int a = half * NH + t;
            const float2 cs = s_cs[t];
            const float X = (float)(xg + p) - CTR;
            const float u  = fmaf(cs.y, Y, fmaf(cs.x, X, CTR));
            const float fl = floorf(u);
            const float wx = u - fl;
            const int i0 = (int)fl;            // in [-27, 153]
            g.w0 = 1.0f - wx;                  // unmasked: margins hold fp8(-0.5)
            g.w1 = wx;
            g.voff = (a * UW + (i0 + 32)) * LZ * 2;
        } else {
            g.w0 = 0.f; g.w1 = 0.f; g.voff = 0; // pad entry: harmless prefetch
        }
        g.pad = 0;
        s_geo[t][p] = g;
    }
    __syncthreads();

    const int zo = tid % 24;  // 8 consecutive z per lane
    const int px = tid / 24;  // 0..7
    const unsigned char* base = pb + zo * 16;

    v2f acc[8]; // acc[j] = (w0-part, w1-part) for z = j
#pragma unroll
    for (int j = 0; j < 8; ++j) acc[j] = (v2f){0.f, 0.f};

    // depth-4 software pipeline (branch-free via padded geo table)
    uint4 T[4];
    v2f   W[4];
#pragma unroll
    for (int k = 0; k < 4; ++k) {
        const GeoP g = s_geo[k][px];
        W[k] = (v2f){g.w0, g.w1};
        T[k] = *reinterpret_cast<const uint4*>(base + g.voff);
    }

    for (int t0 = 0; t0 < NH; t0 += 4) {
#pragma unroll
        for (int k = 0; k < 4; ++k) {
            const uint4 cur = T[k];
            const v2f cw = W[k];
            const GeoP g = s_geo[t0 + k + 4][px]; // pad entries cover tail
            W[k] = (v2f){g.w0, g.w1};
            T[k] = *reinterpret_cast<const uint4*>(base + g.voff);
            const unsigned int* q = &cur.x;
#pragma unroll
            for (int d = 0; d < 4; ++d) {
                const v2f lo = __builtin_amdgcn_cvt_pk_f32_fp8((int)q[d], false); // (t0,t1) z=2d
                const v2f hi = __builtin_amdgcn_cvt_pk_f32_fp8((int)q[d], true);  // (t0,t1) z=2d+1
                acc[2*d + 0] = acc[2*d + 0] + cw * lo; // v_pk_fma_f32
                acc[2*d + 1] = acc[2*d + 1] + cw * hi;
            }
        }
    }

    // partial = sum_w0part + sum_w1part + 0.5 * (sum of w over this half == 60)
    const float inv = (float)(1.0 / (120.0 + 1e-11));
    float* op = out + (size_t)(y * LR + xg + px) * LZ + zo * 8;
#pragma unroll
    for (int j = 0; j < 8; ++j) {
        atomicAdd(op + j, (acc[j][0] + acc[j][1] + 30.0f) * inv);
    }
}

// ============ v5 fallback (smaller workspace): fp8 taps, 8 z/lane ===========
struct __align__(16) Geo {
    float w0, w1;
    int b0, b1;
};

__global__ __launch_bounds__(256) void cvt_fp8(const float* __restrict__ in,
                                               unsigned int* __restrict__ out8,
                                               int n16) {
    const int i = blockIdx.x * 256 + threadIdx.x;
    if (i >= n16) return;
    const float4* p = reinterpret_cast<const float4*>(in) + (size_t)i * 4;
    uint4 o;
    unsigned int* od = &o.x;
#pragma unroll
    for (int d = 0; d < 4; ++d) {
        const float4 f = p[d];
        int w = __builtin_amdgcn_cvt_pk_fp8_f32(f.x - 0.5f, f.y - 0.5f, 0, false);
        w = __builtin_amdgcn_cvt_pk_fp8_f32(f.z - 0.5f, f.w - 0.5f, w, true);
        od[d] = (unsigned int)w;
    }
    reinterpret_cast<uint4*>(out8)[i] = o;
}

__device__ inline void blend8(v2f acc[4], float w0, float w1,
                              const uint2& t0, const uint2& t1) {
    const v2f W0 = {w0, w0};
    const v2f W1 = {w1, w1};
    const unsigned int* q0 = &t0.x;
    const unsigned int* q1 = &t1.x;
#pragma unroll
    for (int d = 0; d < 2; ++d) {
        const v2f a_lo = __builtin_amdgcn_cvt_pk_f32_fp8((int)q0[d], false);
        const v2f a_hi = __builtin_amdgcn_cvt_pk_f32_fp8((int)q0[d], true);
        const v2f b_lo = __builtin_amdgcn_cvt_pk_f32_fp8((int)q1[d], false);
        const v2f b_hi = __builtin_amdgcn_cvt_pk_f32_fp8((int)q1[d], true);
        acc[2 * d + 0] = acc[2 * d + 0] + W0 * a_lo + W1 * b_lo;
        acc[2 * d + 1] = acc[2 * d + 1] + W0 * a_hi + W1 * b_hi;
    }
}

__global__ __launch_bounds__(192, 6) void bp_v5(const unsigned char* __restrict__ img,
                                                float* __restrict__ out) {
    __shared__ float2 s_cs[NA];
    __shared__ Geo s_geo[NA][8];
    __shared__ float s_sumw[8];

    const int tid = threadIdx.x;
    if (tid < NA) {
        const float ang = (float)tid * (float)(2.0 * M_PI / (double)NA);
        const float phi = (float)(1.5 * M_PI) - ang;
        s_cs[tid] = make_float2(cosf(phi), sinf(phi));
    }
    __syncthreads();

    const int bid = blockIdx.x;
    const int swz = (bid & 7) * 256 + (bid >> 3);
    const int y  = swz >> 4;
    const int xg = (swz & 15) << 3;

    const float Y = (float)y - CTR;
    for (int e = tid; e < 8 * NA; e += 192) {
        const int p = e & 7;
        const int a = e >> 3;
        const float2 cs = s_cs[a];
        const float X = (float)(xg + p) - CTR;
        const float u  = fmaf(cs.y, Y, fmaf(cs.x, X, CTR));
        const float fl = floorf(u);
        const float wx = u - fl;
        const int i0 = (int)fl;
        Geo g;
        g.w0 = ((unsigned)i0 < 128u) ? (1.0f - wx) : 0.0f;
        g.w1 = ((unsigned)(i0 + 1) < 128u) ? wx : 0.0f;
        const int o0 = min(max(i0, 0), LR - 1);
        const int o1 = min(max(i0 + 1, 0), LR - 1);
        g.b0 = (a * LR + o0) * LZ;
        g.b1 = (a * LR + o1) * LZ;
        s_geo[a][p] = g;
    }
    __syncthreads();

    if (tid < 8) {
        float s = 0.f;
        for (int a = 0; a < NA; ++a) s += s_geo[a][tid].w0 + s_geo[a][tid].w1;
        s_sumw[tid] = s;
    }
    __syncthreads();

    const int zo = tid % 24;
    const int px = tid / 24;
    const unsigned char* base = img + zo * 8;

    v2f acc[4];
#pragma unroll
    for (int j = 0; j < 4; ++j) acc[j] = (v2f){0.f, 0.f};

    Geo ga = s_geo[0][px];
    Geo gb = s_geo[1][px];
    uint2 A0 = *reinterpret_cast<const uint2*>(base + ga.b0);
    uint2 A1 = *reinterpret_cast<const uint2*>(base + ga.b1);
    uint2 B0 = *reinterpret_cast<const uint2*>(base + gb.b0);
    uint2 B1 = *reinterpret_cast<const uint2*>(base + gb.b1);

    for (int a = 0; a < NA - 2; a += 2) {
        const Geo gn = s_geo[a + 2][px];
        const uint2 N0 = *reinterpret_cast<const uint2*>(base + gn.b0);
        const uint2 N1 = *reinterpret_cast<const uint2*>(base + gn.b1);
        blend8(acc, ga.w0, ga.w1, A0, A1);
        ga = gn; A0 = N0; A1 = N1;
        const Geo gm = s_geo[a + 3][px];
        const uint2 M0 = *reinterpret_cast<const uint2*>(base + gm.b0);
        const uint2 M1 = *reinterpret_cast<const uint2*>(base + gm.b1);
        blend8(acc, gb.w0, gb.w1, B0, B1);
        gb = gm; B0 = M0; B1 = M1;
    }
    blend8(acc, ga.w0, ga.w1, A0, A1);
    blend8(acc, gb.w0, gb.w1, B0, B1);

    const float inv = (float)(1.0 / (120.0 + 1e-11));
    const float half_sw = 0.5f * s_sumw[px];
    float* op = out + ((size_t)(y * LR + xg + px)) * LZ + zo * 8;
    float4 r0, r1;
    r0.x = (acc[0][0] + half_sw) * inv;
    r0.y = (acc[0][1] + half_sw) * inv;
    r0.z = (acc[1][0] + half_sw) * inv;
    r0.w = (acc[1][1] + half_sw) * inv;
    r1.x = (acc[2][0] + half_sw) * inv;
    r1.y = (acc[2][1] + half_sw) * inv;
    r1.z = (acc[3][0] + half_sw) * inv;
    r1.w = (acc[3][1] + half_sw) * inv;
    *reinterpret_cast<float4*>(op)     = r0;
    *reinterpret_cast<float4*>(op + 4) = r1;
}

// ============ fp32 fallback (no workspace) ==================================
__global__ __launch_bounds__(192) void bp_main(const float* __restrict__ img,
                                               float* __restrict__ out) {
    __shared__ float s_cp[NA];
    __shared__ float s_sp[NA];
    struct __align__(16) GeoF { float w0, w1; int off0, off1; };
    __shared__ GeoF s_geo[4][NA];

    const int tx = threadIdx.x;
    const int py = threadIdx.y;
    const int tid = py * 48 + tx;
    const int y  = blockIdx.x >> 5;
    const int xg = (blockIdx.x & 31) << 2;

    if (tid < NA) {
        const float ang = (float)tid * (float)(2.0 * M_PI / (double)NA);
        const float phi = (float)(1.5 * M_PI) - ang;
        s_cp[tid] = cosf(phi);
        s_sp[tid] = sinf(phi);
    }
    __syncthreads();

    for (int e = tid; e < 4 * NA; e += 192) {
        const int a = e % NA;
        const int p = e / NA;
        const float cp = s_cp[a];
        const float sp = s_sp[a];
        const float Yf = (float)y - CTR;
        const float Xf = (float)(xg + p) - CTR;
        const float u = sp * Yf + cp * Xf + CTR;
        const float fl = floorf(u);
        const float wx = u - fl;
        const int i0 = (int)fl;
        GeoF g;
        g.w0 = (i0 >= 0 && i0 < LR) ? (1.0f - wx) : 0.0f;
        g.w1 = (i0 >= -1 && i0 < LR - 1) ? wx : 0.0f;
        const int o0 = min(max(i0, 0), LR - 1);
        const int o1 = min(max(i0 + 1, 0), LR - 1);
        g.off0 = (a * LR + o0) * LZ;
        g.off1 = (a * LR + o1) * LZ;
        s_geo[p][a] = g;
    }
    __syncthreads();

    const int zb = tx << 2;
    float4 acc = make_float4(0.f, 0.f, 0.f, 0.f);
#pragma unroll 4
    for (int a = 0; a < NA; ++a) {
        const GeoF g = s_geo[py][a];
        const float4 v0 = *reinterpret_cast<const float4*>(img + g.off0 + zb);
        const float4 v1 = *reinterpret_cast<const float4*>(img + g.off1 + zb);
        acc.x = fmaf(g.w0, v0.x, fmaf(g.w1, v1.x, acc.x));
        acc.y = fmaf(g.w0, v0.y, fmaf(g.w1, v1.y, acc.y));
        acc.z = fmaf(g.w0, v0.z, fmaf(g.w1, v1.z, acc.z));
        acc.w = fmaf(g.w0, v0.w, fmaf(g.w1, v1.w, acc.w));
    }
    const float inv = (float)(1.0 / (120.0 + 1e-11));
    float4 r;
    r.x = acc.x * inv; r.y = acc.y * inv; r.z = acc.z * inv; r.w = acc.w * inv;
    *reinterpret_cast<float4*>(out + (y * LR + xg + py) * LZ + zb) = r;
}

} // namespace

extern "C" void kernel_launch(void* const* d_in, const int* in_sizes, int n_in,
                              void* d_out, int out_size, void* d_ws, size_t ws_size,
                              hipStream_t stream) {
    const float* img = (const float*)d_in[0];
    float* out = (float*)d_out;
    const int n = NA * LR * LZ;                       // 2,949,120
    const size_t pair_bytes = (size_t)NA * UW * LZ * 2; // 8,847,360
    const size_t fp8_bytes  = (size_t)n;              // 2,949,120

    if (ws_size >= pair_bytes) {
        unsigned short* pb = (unsigned short*)d_ws;
        hipLaunchKernelGGL(cvt_pairs, dim3(2160), dim3(256), 0, stream, img, pb);
        hipMemsetAsync(d_out, 0, (size_t)out_size * sizeof(float), stream);
        hipLaunchKernelGGL(bp_v6, dim3(4096), dim3(192), 0, stream,
                           (const unsigned char*)pb, out);
    } else if (ws_size >= fp8_bytes) {
        unsigned int* img8 = (unsigned int*)d_ws;
        const int n16 = n / 16;
        hipLaunchKernelGGL(cvt_fp8, dim3((n16 + 255) / 256), dim3(256), 0, stream,
                           img, img8, n16);
        hipLaunchKernelGGL(bp_v5, dim3(128 * 16), dim3(192), 0, stream,
                           (const unsigned char*)img8, out);
    } else {
        hipLaunchKernelGGL(bp_main, dim3(128 * 32), dim3(48, 4), 0, stream,
                           img, out);
    }
}

// Round 7
// 46.650 us; speedup vs baseline: 3.9891x; 3.9891x over previous
//
#include <hip/hip_runtime.h>
#include <math.h>

namespace {

constexpr int NA = 120;
constexpr int LR = 128;
constexpr int LZ = 192;
constexpr int UW = 192;   // padded u-width of the pair buffer
constexpr float CTR = 63.5f; // unpadded-space center: (LP-1)/2 - PAD = 90.5 - 27

typedef float v2f __attribute__((ext_vector_type(2)));

// ============ pair-buffer pre-pass =========================================
// pb[a][u'][z] = (fp8(v[a][u'-32][z]-0.5), fp8(v[a][u'-31][z]-0.5)), 2 B/pair.
// Rows outside [0,128) are the zero-pad region -> stored fp8(-0.5), so the
// main kernel needs NO masks: w*(v-0.5) + 0.5*w == w*v for v==0 too.
__global__ __launch_bounds__(256) void cvt_pairs(const float* __restrict__ img,
                                                 unsigned short* __restrict__ pb) {
    const int idx = blockIdx.x * 256 + threadIdx.x; // 120*192*24 = 552960 exact
    const int zc = idx % (LZ / 8);
    const int t  = idx / (LZ / 8);
    const int up = t % UW;
    const int a  = t / UW;
    const int r0 = up - 32;
    const int r1 = up - 31;
    const int z0 = zc * 8;

    float v0[8], v1[8];
    if (r0 >= 0 && r0 < LR) {
        const float4 x = *reinterpret_cast<const float4*>(img + (a * LR + r0) * LZ + z0);
        const float4 y = *reinterpret_cast<const float4*>(img + (a * LR + r0) * LZ + z0 + 4);
        v0[0]=x.x; v0[1]=x.y; v0[2]=x.z; v0[3]=x.w;
        v0[4]=y.x; v0[5]=y.y; v0[6]=y.z; v0[7]=y.w;
    } else {
#pragma unroll
        for (int j = 0; j < 8; ++j) v0[j] = 0.f;
    }
    if (r1 >= 0 && r1 < LR) {
        const float4 x = *reinterpret_cast<const float4*>(img + (a * LR + r1) * LZ + z0);
        const float4 y = *reinterpret_cast<const float4*>(img + (a * LR + r1) * LZ + z0 + 4);
        v1[0]=x.x; v1[1]=x.y; v1[2]=x.z; v1[3]=x.w;
        v1[4]=y.x; v1[5]=y.y; v1[6]=y.z; v1[7]=y.w;
    } else {
#pragma unroll
        for (int j = 0; j < 8; ++j) v1[j] = 0.f;
    }

    uint4 o;
    unsigned int* od = &o.x;
#pragma unroll
    for (int d = 0; d < 4; ++d) {
        // dword d = bytes (t0_z, t1_z, t0_{z+1}, t1_{z+1}) for z = 2d
        int w = __builtin_amdgcn_cvt_pk_fp8_f32(v0[2*d] - 0.5f, v1[2*d] - 0.5f, 0, false);
        w = __builtin_amdgcn_cvt_pk_fp8_f32(v0[2*d+1] - 0.5f, v1[2*d+1] - 0.5f, w, true);
        od[d] = (unsigned int)w;
    }
    *reinterpret_cast<uint4*>(pb + ((size_t)(a * UW + up) * LZ + z0)) = o;
}

// ============ main: 120 angles/block, pair taps, depth-4 ring, plain stores =
struct __align__(16) GeoP {
    float w0, w1;
    unsigned int boff; // byte offset of the pair row in pb
    int pad;
};

__global__ __launch_bounds__(192, 6) void bp_v7(const unsigned char* __restrict__ pb,
                                                float* __restrict__ out) {
    __shared__ float2 s_cs[NA];
    __shared__ GeoP s_geo[NA + 4][8]; // +4 zero-weight pad rows (branch-free ring)

    const int tid = threadIdx.x; // 0..191

    if (tid < NA) {
        const float ang = (float)tid * (float)(2.0 * M_PI / (double)NA);
        const float phi = (float)(1.5 * M_PI) - ang;
        s_cs[tid] = make_float2(cosf(phi), sinf(phi));
    }
    __syncthreads();

    // 2048 blocks; XCD-aware chunked swizzle (bijective: 2048 % 8 == 0)
    const int bid = blockIdx.x;
    const int swz = (bid & 7) * 256 + (bid >> 3);
    const int y  = swz >> 4;        // 0..127
    const int xg = (swz & 15) << 3; // x base, step 8

    // geometry table: 8 px * (120+4) rows, angle-major (conflict-free reads)
    const float Y = (float)y - CTR;
    for (int e = tid; e < 8 * (NA + 4); e += 192) {
        const int p = e & 7;
        const int t = e >> 3;
        GeoP g;
        if (t < NA) {
            const float2 cs = s_cs[t];
            const float X = (float)(xg + p) - CTR;
            const float u  = fmaf(cs.y, Y, fmaf(cs.x, X, CTR));
            const float fl = floorf(u);
            const float wx = u - fl;
            const int i0 = (int)fl;           // in [-27, 153]
            g.w0 = 1.0f - wx;                 // unmasked: margins hold fp8(-0.5)
            g.w1 = wx;
            g.boff = (unsigned)((t * UW + (i0 + 32)) * LZ * 2);
        } else {
            g.w0 = 0.f; g.w1 = 0.f; g.boff = 0; // pad row: harmless prefetch
        }
        g.pad = 0;
        s_geo[t][p] = g;
    }
    __syncthreads();

    const int zo = tid % 24;  // 8 consecutive z per lane
    const int px = tid / 24;  // 0..7
    const unsigned int zob = (unsigned)(zo * 16);

    v2f acc[8]; // acc[j] = (sum w0*t0, sum w1*t1) for z = j
#pragma unroll
    for (int j = 0; j < 8; ++j) acc[j] = (v2f){0.f, 0.f};

    // depth-4 software pipeline (branch-free via padded geo table)
    uint4 T[4];
    v2f   W[4];
#pragma unroll
    for (int k = 0; k < 4; ++k) {
        const GeoP g = s_geo[k][px];
        W[k] = (v2f){g.w0, g.w1};
        T[k] = *reinterpret_cast<const uint4*>(pb + (g.boff + zob));
    }

    for (int t0 = 0; t0 < NA; t0 += 4) {
#pragma unroll
        for (int k = 0; k < 4; ++k) {
            const uint4 cur = T[k];
            const v2f cw = W[k];
            const GeoP g = s_geo[t0 + k + 4][px]; // pad rows cover the tail
            W[k] = (v2f){g.w0, g.w1};
            T[k] = *reinterpret_cast<const uint4*>(pb + (g.boff + zob));
            const unsigned int* q = &cur.x;
#pragma unroll
            for (int d = 0; d < 4; ++d) {
                const v2f lo = __builtin_amdgcn_cvt_pk_f32_fp8((int)q[d], false); // taps z=2d
                const v2f hi = __builtin_amdgcn_cvt_pk_f32_fp8((int)q[d], true);  // taps z=2d+1
                acc[2*d + 0] = acc[2*d + 0] + cw * lo; // v_pk_fma_f32
                acc[2*d + 1] = acc[2*d + 1] + cw * hi;
            }
        }
    }

    // out = (acc_w0 + acc_w1 + 0.5 * sum(w) == 120) / (120 + 1e-11)
    const float inv = (float)(1.0 / (120.0 + 1e-11));
    float* op = out + (size_t)(y * LR + xg + px) * LZ + zo * 8;
    float4 r0, r1;
    r0.x = (acc[0][0] + acc[0][1] + 60.0f) * inv;
    r0.y = (acc[1][0] + acc[1][1] + 60.0f) * inv;
    r0.z = (acc[2][0] + acc[2][1] + 60.0f) * inv;
    r0.w = (acc[3][0] + acc[3][1] + 60.0f) * inv;
    r1.x = (acc[4][0] + acc[4][1] + 60.0f) * inv;
    r1.y = (acc[5][0] + acc[5][1] + 60.0f) * inv;
    r1.z = (acc[6][0] + acc[6][1] + 60.0f) * inv;
    r1.w = (acc[7][0] + acc[7][1] + 60.0f) * inv;
    *reinterpret_cast<float4*>(op)     = r0;
    *reinterpret_cast<float4*>(op + 4) = r1;
}

// ============ v5 fallback (smaller workspace): fp8 taps, 8 z/lane ===========
struct __align__(16) Geo {
    float w0, w1;
    int b0, b1;
};

__global__ __launch_bounds__(256) void cvt_fp8(const float* __restrict__ in,
                                               unsigned int* __restrict__ out8,
                                               int n16) {
    const int i = blockIdx.x * 256 + threadIdx.x;
    if (i >= n16) return;
    const float4* p = reinterpret_cast<const float4*>(in) + (size_t)i * 4;
    uint4 o;
    unsigned int* od = &o.x;
#pragma unroll
    for (int d = 0; d < 4; ++d) {
        const float4 f = p[d];
        int w = __builtin_amdgcn_cvt_pk_fp8_f32(f.x - 0.5f, f.y - 0.5f, 0, false);
        w = __builtin_amdgcn_cvt_pk_fp8_f32(f.z - 0.5f, f.w - 0.5f, w, true);
        od[d] = (unsigned int)w;
    }
    reinterpret_cast<uint4*>(out8)[i] = o;
}

__device__ inline void blend8(v2f acc[4], float w0, float w1,
                              const uint2& t0, const uint2& t1) {
    const v2f W0 = {w0, w0};
    const v2f W1 = {w1, w1};
    const unsigned int* q0 = &t0.x;
    const unsigned int* q1 = &t1.x;
#pragma unroll
    for (int d = 0; d < 2; ++d) {
        const v2f a_lo = __builtin_amdgcn_cvt_pk_f32_fp8((int)q0[d], false);
        const v2f a_hi = __builtin_amdgcn_cvt_pk_f32_fp8((int)q0[d], true);
        const v2f b_lo = __builtin_amdgcn_cvt_pk_f32_fp8((int)q1[d], false);
        const v2f b_hi = __builtin_amdgcn_cvt_pk_f32_fp8((int)q1[d], true);
        acc[2 * d + 0] = acc[2 * d + 0] + W0 * a_lo + W1 * b_lo;
        acc[2 * d + 1] = acc[2 * d + 1] + W0 * a_hi + W1 * b_hi;
    }
}

__global__ __launch_bounds__(192, 6) void bp_v5(const unsigned char* __restrict__ img,
                                                float* __restrict__ out) {
    __shared__ float2 s_cs[NA];
    __shared__ Geo s_geo[NA][8];
    __shared__ float s_sumw[8];

    const int tid = threadIdx.x;
    if (tid < NA) {
        const float ang = (float)tid * (float)(2.0 * M_PI / (double)NA);
        const float phi = (float)(1.5 * M_PI) - ang;
        s_cs[tid] = make_float2(cosf(phi), sinf(phi));
    }
    __syncthreads();

    const int bid = blockIdx.x;
    const int swz = (bid & 7) * 256 + (bid >> 3);
    const int y  = swz >> 4;
    const int xg = (swz & 15) << 3;

    const float Y = (float)y - CTR;
    for (int e = tid; e < 8 * NA; e += 192) {
        const int p = e & 7;
        const int a = e >> 3;
        const float2 cs = s_cs[a];
        const float X = (float)(xg + p) - CTR;
        const float u  = fmaf(cs.y, Y, fmaf(cs.x, X, CTR));
        const float fl = floorf(u);
        const float wx = u - fl;
        const int i0 = (int)fl;
        Geo g;
        g.w0 = ((unsigned)i0 < 128u) ? (1.0f - wx) : 0.0f;
        g.w1 = ((unsigned)(i0 + 1) < 128u) ? wx : 0.0f;
        const int o0 = min(max(i0, 0), LR - 1);
        const int o1 = min(max(i0 + 1, 0), LR - 1);
        g.b0 = (a * LR + o0) * LZ;
        g.b1 = (a * LR + o1) * LZ;
        s_geo[a][p] = g;
    }
    __syncthreads();

    if (tid < 8) {
        float s = 0.f;
        for (int a = 0; a < NA; ++a) s += s_geo[a][tid].w0 + s_geo[a][tid].w1;
        s_sumw[tid] = s;
    }
    __syncthreads();

    const int zo = tid % 24;
    const int px = tid / 24;
    const unsigned char* base = img + zo * 8;

    v2f acc[4];
#pragma unroll
    for (int j = 0; j < 4; ++j) acc[j] = (v2f){0.f, 0.f};

    Geo ga = s_geo[0][px];
    Geo gb = s_geo[1][px];
    uint2 A0 = *reinterpret_cast<const uint2*>(base + ga.b0);
    uint2 A1 = *reinterpret_cast<const uint2*>(base + ga.b1);
    uint2 B0 = *reinterpret_cast<const uint2*>(base + gb.b0);
    uint2 B1 = *reinterpret_cast<const uint2*>(base + gb.b1);

    for (int a = 0; a < NA - 2; a += 2) {
        const Geo gn = s_geo[a + 2][px];
        const uint2 N0 = *reinterpret_cast<const uint2*>(base + gn.b0);
        const uint2 N1 = *reinterpret_cast<const uint2*>(base + gn.b1);
        blend8(acc, ga.w0, ga.w1, A0, A1);
        ga = gn; A0 = N0; A1 = N1;
        const Geo gm = s_geo[a + 3][px];
        const uint2 M0 = *reinterpret_cast<const uint2*>(base + gm.b0);
        const uint2 M1 = *reinterpret_cast<const uint2*>(base + gm.b1);
        blend8(acc, gb.w0, gb.w1, B0, B1);
        gb = gm; B0 = M0; B1 = M1;
    }
    blend8(acc, ga.w0, ga.w1, A0, A1);
    blend8(acc, gb.w0, gb.w1, B0, B1);

    const float inv = (float)(1.0 / (120.0 + 1e-11));
    const float half_sw = 0.5f * s_sumw[px];
    float* op = out + ((size_t)(y * LR + xg + px)) * LZ + zo * 8;
    float4 r0, r1;
    r0.x = (acc[0][0] + half_sw) * inv;
    r0.y = (acc[0][1] + half_sw) * inv;
    r0.z = (acc[1][0] + half_sw) * inv;
    r0.w = (acc[1][1] + half_sw) * inv;
    r1.x = (acc[2][0] + half_sw) * inv;
    r1.y = (acc[2][1] + half_sw) * inv;
    r1.z = (acc[3][0] + half_sw) * inv;
    r1.w = (acc[3][1] + half_sw) * inv;
    *reinterpret_cast<float4*>(op)     = r0;
    *reinterpret_cast<float4*>(op + 4) = r1;
}

// ============ fp32 fallback (no workspace) ==================================
__global__ __launch_bounds__(192) void bp_main(const float* __restrict__ img,
                                               float* __restrict__ out) {
    __shared__ float s_cp[NA];
    __shared__ float s_sp[NA];
    struct __align__(16) GeoF { float w0, w1; int off0, off1; };
    __shared__ GeoF s_geo[4][NA];

    const int tx = threadIdx.x;
    const int py = threadIdx.y;
    const int tid = py * 48 + tx;
    const int y  = blockIdx.x >> 5;
    const int xg = (blockIdx.x & 31) << 2;

    if (tid < NA) {
        const float ang = (float)tid * (float)(2.0 * M_PI / (double)NA);
        const float phi = (float)(1.5 * M_PI) - ang;
        s_cp[tid] = cosf(phi);
        s_sp[tid] = sinf(phi);
    }
    __syncthreads();

    for (int e = tid; e < 4 * NA; e += 192) {
        const int a = e % NA;
        const int p = e / NA;
        const float cp = s_cp[a];
        const float sp = s_sp[a];
        const float Yf = (float)y - CTR;
        const float Xf = (float)(xg + p) - CTR;
        const float u = sp * Yf + cp * Xf + CTR;
        const float fl = floorf(u);
        const float wx = u - fl;
        const int i0 = (int)fl;
        GeoF g;
        g.w0 = (i0 >= 0 && i0 < LR) ? (1.0f - wx) : 0.0f;
        g.w1 = (i0 >= -1 && i0 < LR - 1) ? wx : 0.0f;
        const int o0 = min(max(i0, 0), LR - 1);
        const int o1 = min(max(i0 + 1, 0), LR - 1);
        g.off0 = (a * LR + o0) * LZ;
        g.off1 = (a * LR + o1) * LZ;
        s_geo[p][a] = g;
    }
    __syncthreads();

    const int zb = tx << 2;
    float4 acc = make_float4(0.f, 0.f, 0.f, 0.f);
#pragma unroll 4
    for (int a = 0; a < NA; ++a) {
        const GeoF g = s_geo[py][a];
        const float4 v0 = *reinterpret_cast<const float4*>(img + g.off0 + zb);
        const float4 v1 = *reinterpret_cast<const float4*>(img + g.off1 + zb);
        acc.x = fmaf(g.w0, v0.x, fmaf(g.w1, v1.x, acc.x));
        acc.y = fmaf(g.w0, v0.y, fmaf(g.w1, v1.y, acc.y));
        acc.z = fmaf(g.w0, v0.z, fmaf(g.w1, v1.z, acc.z));
        acc.w = fmaf(g.w0, v0.w, fmaf(g.w1, v1.w, acc.w));
    }
    const float inv = (float)(1.0 / (120.0 + 1e-11));
    float4 r;
    r.x = acc.x * inv; r.y = acc.y * inv; r.z = acc.z * inv; r.w = acc.w * inv;
    *reinterpret_cast<float4*>(out + (y * LR + xg + py) * LZ + zb) = r;
}

} // namespace

extern "C" void kernel_launch(void* const* d_in, const int* in_sizes, int n_in,
                              void* d_out, int out_size, void* d_ws, size_t ws_size,
                              hipStream_t stream) {
    const float* img = (const float*)d_in[0];
    float* out = (float*)d_out;
    const int n = NA * LR * LZ;                         // 2,949,120
    const size_t pair_bytes = (size_t)NA * UW * LZ * 2; // 8,847,360
    const size_t fp8_bytes  = (size_t)n;                // 2,949,120

    if (ws_size >= pair_bytes) {
        unsigned short* pb = (unsigned short*)d_ws;
        hipLaunchKernelGGL(cvt_pairs, dim3(2160), dim3(256), 0, stream, img, pb);
        hipLaunchKernelGGL(bp_v7, dim3(2048), dim3(192), 0, stream,
                           (const unsigned char*)pb, out);
    } else if (ws_size >= fp8_bytes) {
        unsigned int* img8 = (unsigned int*)d_ws;
        const int n16 = n / 16;
        hipLaunchKernelGGL(cvt_fp8, dim3((n16 + 255) / 256), dim3(256), 0, stream,
                           img, img8, n16);
        hipLaunchKernelGGL(bp_v5, dim3(128 * 16), dim3(192), 0, stream,
                           (const unsigned char*)img8, out);
    } else {
        hipLaunchKernelGGL(bp_main, dim3(128 * 32), dim3(48, 4), 0, stream,
                           img, out);
    }
}